// Round 1
// baseline (3366.716 us; speedup 1.0000x reference)
//
#include <hip/hip_runtime.h>

// SingleStreamBlockLoraProcessor — MI355X bf16 MFMA implementation.
// Shapes: B=1, L=2560, DIM=3072, HEADS=24, HD=128, MLP=12288, RANK=16.
// Inputs fp32, output fp32; internal compute bf16 (tolerance is bf16-grade).

using u16 = unsigned short;
using u32 = unsigned int;

typedef __attribute__((ext_vector_type(8))) __bf16 bf16x8;
typedef __attribute__((ext_vector_type(4))) float f32x4;

#define DEV static __device__ __forceinline__

constexpr int LQ   = 2560;
constexpr int DIMC = 3072;
constexpr int NH   = 24;
constexpr int HD   = 128;
constexpr int NTOT = 21504;   // 3*DIM + MLP
constexpr int QKVW = 9216;    // 3*DIM
constexpr int CATW = 15360;   // DIM + MLP
constexpr int RK   = 16;

DEV u16 f2bf(float f) {
  union { float f; u32 u; } v; v.f = f;
  u32 r = v.u + 0x7FFFu + ((v.u >> 16) & 1u);
  return (u16)(r >> 16);
}
DEV float bflo(u32 u) { union { u32 u; float f; } v; v.u = u << 16; return v.f; }
DEV float bfhi(u32 u) { union { u32 u; float f; } v; v.u = u & 0xFFFF0000u; return v.f; }
DEV void unpack8(uint4 u, float* f) {
  f[0]=bflo(u.x); f[1]=bfhi(u.x); f[2]=bflo(u.y); f[3]=bfhi(u.y);
  f[4]=bflo(u.z); f[5]=bfhi(u.z); f[6]=bflo(u.w); f[7]=bfhi(u.w);
}
DEV void gload_lds16(const void* g, void* l) {
  __builtin_amdgcn_global_load_lds((const __attribute__((address_space(1))) void*)g,
                                   (__attribute__((address_space(3))) void*)l, 16, 0, 0);
}
DEV float gelu_tanh(float v) {
  float u = 0.7978845608028654f * (v + 0.044715f * v * v * v);
  float e = __expf(2.0f * u);
  float t = 1.0f - 2.0f / (e + 1.0f);
  return 0.5f * v * (1.0f + t);
}

// ---------------- fp32 -> bf16 conversion ----------------
__global__ __launch_bounds__(256) void cvt_bf16(const float* __restrict__ in,
                                                u16* __restrict__ out, long n) {
  long i = ((long)blockIdx.x * 256 + threadIdx.x) * 8;
  const long stride = (long)gridDim.x * 256 * 8;
  for (; i < n; i += stride) {
    float4 a = *(const float4*)(in + i);
    float4 b = *(const float4*)(in + i + 4);
    uint4 o;
    o.x = (u32)f2bf(a.x) | ((u32)f2bf(a.y) << 16);
    o.y = (u32)f2bf(a.z) | ((u32)f2bf(a.w) << 16);
    o.z = (u32)f2bf(b.x) | ((u32)f2bf(b.y) << 16);
    o.w = (u32)f2bf(b.z) | ((u32)f2bf(b.w) << 16);
    *(uint4*)(out + i) = o;
  }
}

// ---------------- mod = silu(vec) @ mod_w.T + mod_b ----------------
__global__ __launch_bounds__(256) void mod_kernel(const float* __restrict__ vec,
    const float* __restrict__ mw, const float* __restrict__ mb, float* __restrict__ mo) {
  const int j = blockIdx.x * 4 + (threadIdx.x >> 6);
  const int lane = threadIdx.x & 63;
  const float* wr_ = mw + (size_t)j * DIMC;
  float s = 0.f;
  for (int i = lane * 4; i < DIMC; i += 256) {
    float4 w4 = *(const float4*)(wr_ + i);
    float4 v4 = *(const float4*)(vec + i);
    float s0 = v4.x / (1.f + __expf(-v4.x));
    float s1 = v4.y / (1.f + __expf(-v4.y));
    float s2 = v4.z / (1.f + __expf(-v4.z));
    float s3 = v4.w / (1.f + __expf(-v4.w));
    s += s0 * w4.x + s1 * w4.y + s2 * w4.z + s3 * w4.w;
  }
  #pragma unroll
  for (int o = 32; o; o >>= 1) s += __shfl_down(s, o);
  if (lane == 0) mo[j] = s + mb[j];
}

// ---------------- LayerNorm + modulate -> x_mod (bf16) ----------------
__global__ __launch_bounds__(256) void ln_mod(const float* __restrict__ x,
    const float* __restrict__ modv, u16* __restrict__ xmod) {
  const int row = blockIdx.x, tid = threadIdx.x;
  const float* xr = x + (size_t)row * DIMC;
  float4 v0 = *(const float4*)(xr + tid * 4);
  float4 v1 = *(const float4*)(xr + tid * 4 + 1024);
  float4 v2 = *(const float4*)(xr + tid * 4 + 2048);
  float s  = v0.x + v0.y + v0.z + v0.w + v1.x + v1.y + v1.z + v1.w + v2.x + v2.y + v2.z + v2.w;
  float ss = v0.x*v0.x + v0.y*v0.y + v0.z*v0.z + v0.w*v0.w
           + v1.x*v1.x + v1.y*v1.y + v1.z*v1.z + v1.w*v1.w
           + v2.x*v2.x + v2.y*v2.y + v2.z*v2.z + v2.w*v2.w;
  #pragma unroll
  for (int o = 32; o; o >>= 1) { s += __shfl_down(s, o); ss += __shfl_down(ss, o); }
  __shared__ float rs[4], rss[4];
  const int lane = tid & 63, wv = tid >> 6;
  if (lane == 0) { rs[wv] = s; rss[wv] = ss; }
  __syncthreads();
  s = rs[0] + rs[1] + rs[2] + rs[3]; ss = rss[0] + rss[1] + rss[2] + rss[3];
  const float mu = s * (1.0f / 3072.0f);
  const float rstd = rsqrtf(ss * (1.0f / 3072.0f) - mu * mu + 1e-6f);
  u16* orow = xmod + (size_t)row * DIMC;
  #pragma unroll
  for (int p = 0; p < 3; ++p) {
    const int c = tid * 4 + p * 1024;
    const float4 v = (p == 0) ? v0 : ((p == 1) ? v1 : v2);
    const float4 scv = *(const float4*)(modv + DIMC + c);
    const float4 shv = *(const float4*)(modv + c);
    u32 w0 = (u32)f2bf((1.f + scv.x) * ((v.x - mu) * rstd) + shv.x)
           | ((u32)f2bf((1.f + scv.y) * ((v.y - mu) * rstd) + shv.y) << 16);
    u32 w1 = (u32)f2bf((1.f + scv.z) * ((v.z - mu) * rstd) + shv.z)
           | ((u32)f2bf((1.f + scv.w) * ((v.w - mu) * rstd) + shv.w) << 16);
    uint2 o; o.x = w0; o.y = w1;
    *(uint2*)(orow + c) = o;
  }
}

// ---------------- LoRA down: T[m][16] = X[m][:] @ Wd[16][:]^T ----------------
__global__ __launch_bounds__(256) void lora_down(const u16* __restrict__ X,
    const u16* __restrict__ Wd, float* __restrict__ T, int K) {
  const int m = blockIdx.x;
  const int lane = threadIdx.x & 63, wv = threadIdx.x >> 6;
  const u16* xr = X + (size_t)m * K;
  float a0 = 0, a1 = 0, a2 = 0, a3 = 0;
  for (int c = lane * 8; c < K; c += 512) {
    uint4 xu = *(const uint4*)(xr + c);
    float xv[8]; unpack8(xu, xv);
    float w0[8], w1[8], w2[8], w3[8];
    unpack8(*(const uint4*)(Wd + (size_t)(wv * 4 + 0) * K + c), w0);
    unpack8(*(const uint4*)(Wd + (size_t)(wv * 4 + 1) * K + c), w1);
    unpack8(*(const uint4*)(Wd + (size_t)(wv * 4 + 2) * K + c), w2);
    unpack8(*(const uint4*)(Wd + (size_t)(wv * 4 + 3) * K + c), w3);
    #pragma unroll
    for (int i = 0; i < 8; ++i) {
      a0 += xv[i] * w0[i]; a1 += xv[i] * w1[i];
      a2 += xv[i] * w2[i]; a3 += xv[i] * w3[i];
    }
  }
  #pragma unroll
  for (int o = 32; o; o >>= 1) {
    a0 += __shfl_down(a0, o); a1 += __shfl_down(a1, o);
    a2 += __shfl_down(a2, o); a3 += __shfl_down(a3, o);
  }
  if (lane == 0) {
    float* tp = T + (size_t)m * RK + wv * 4;
    tp[0] = a0; tp[1] = a1; tp[2] = a2; tp[3] = a3;
  }
}

// ---------------- 128x128 MFMA GEMM, C = A @ W^T (+ fused epilogues) ----------------
// EPI=0: GEMM1 -> qkv (bias + LoRA-up) as bf16, and gelu(mlp) into cat[:,3072:]
// EPI=1: GEMM2 -> out = x + gate * (acc + bias + LoRA-up), fp32
template<int EPI>
__global__ __launch_bounds__(256)
void gemm128(const u16* __restrict__ A, const u16* __restrict__ W, int K,
             const float* __restrict__ bias, const u16* __restrict__ up,
             const float* __restrict__ tlow,
             u16* __restrict__ out_qkv, u16* __restrict__ out_cat,
             const float* __restrict__ xres, const float* __restrict__ gate,
             float* __restrict__ outf) {
  __shared__ u16 As[128 * 32];
  __shared__ u16 Bs[128 * 32];
  const int tid = threadIdx.x;
  const int lane = tid & 63, wv = tid >> 6;
  const int bn = blockIdx.x * 128, bm = blockIdx.y * 128;
  const int wr = wv >> 1, wc = wv & 1;
  const int srow = lane >> 2, skof = (lane & 3) * 8;
  const int cidx = lane & 15, rgrp = lane >> 4;
  const int kf = rgrp * 8;

  f32x4 acc[4][4] = {};

  for (int k0 = 0; k0 < K; k0 += 32) {
    #pragma unroll
    for (int r = 0; r < 2; ++r) {
      const int rowblk = (r * 4 + wv) * 16;
      gload_lds16(A + (size_t)(bm + rowblk + srow) * K + k0 + skof, As + rowblk * 32);
      gload_lds16(W + (size_t)(bn + rowblk + srow) * K + k0 + skof, Bs + rowblk * 32);
    }
    __syncthreads();
    bf16x8 af[4], bfr[4];
    #pragma unroll
    for (int i = 0; i < 4; ++i) {
      af[i]  = *(const bf16x8*)(As + (wr * 64 + i * 16 + cidx) * 32 + kf);
      bfr[i] = *(const bf16x8*)(Bs + (wc * 64 + i * 16 + cidx) * 32 + kf);
    }
    #pragma unroll
    for (int mi = 0; mi < 4; ++mi)
      #pragma unroll
      for (int ni = 0; ni < 4; ++ni)
        acc[mi][ni] = __builtin_amdgcn_mfma_f32_16x16x32_bf16(af[mi], bfr[ni], acc[mi][ni], 0, 0, 0);
    __syncthreads();
  }

  const int rowb = bm + wr * 64;
  const int colb = bn + wc * 64;
  if (EPI == 0) {
    if (bn < QKVW) {
      #pragma unroll
      for (int ni = 0; ni < 4; ++ni) {
        const int n = colb + ni * 16 + cidx;
        const float b = bias[n];
        float upv[16];
        unpack8(*(const uint4*)(up + (size_t)n * RK), upv);
        unpack8(*(const uint4*)(up + (size_t)n * RK + 8), upv + 8);
        #pragma unroll
        for (int mi = 0; mi < 4; ++mi) {
          #pragma unroll
          for (int j = 0; j < 4; ++j) {
            const int m = rowb + mi * 16 + rgrp * 4 + j;
            const float* tr = tlow + (size_t)m * RK;
            float v = acc[mi][ni][j] + b;
            #pragma unroll
            for (int i = 0; i < 16; ++i) v += tr[i] * upv[i];
            out_qkv[(size_t)m * QKVW + n] = f2bf(v);
          }
        }
      }
    } else {
      #pragma unroll
      for (int ni = 0; ni < 4; ++ni) {
        const int n = colb + ni * 16 + cidx;
        const float b = bias[n];
        #pragma unroll
        for (int mi = 0; mi < 4; ++mi) {
          #pragma unroll
          for (int j = 0; j < 4; ++j) {
            const int m = rowb + mi * 16 + rgrp * 4 + j;
            out_cat[(size_t)m * CATW + (n - 2 * DIMC)] = f2bf(gelu_tanh(acc[mi][ni][j] + b));
          }
        }
      }
    }
  } else {
    #pragma unroll
    for (int ni = 0; ni < 4; ++ni) {
      const int n = colb + ni * 16 + cidx;
      const float b = bias[n];
      const float g = gate[n];
      float upv[16];
      unpack8(*(const uint4*)(up + (size_t)n * RK), upv);
      unpack8(*(const uint4*)(up + (size_t)n * RK + 8), upv + 8);
      #pragma unroll
      for (int mi = 0; mi < 4; ++mi) {
        #pragma unroll
        for (int j = 0; j < 4; ++j) {
          const int m = rowb + mi * 16 + rgrp * 4 + j;
          const float* tr = tlow + (size_t)m * RK;
          float v = acc[mi][ni][j] + b;
          #pragma unroll
          for (int i = 0; i < 16; ++i) v += tr[i] * upv[i];
          outf[(size_t)m * DIMC + n] = xres[(size_t)m * DIMC + n] + g * v;
        }
      }
    }
  }
}

// ---------------- qkv prep: RMS-norm + RoPE, V transpose ----------------
__global__ __launch_bounds__(256) void qkv_prep(const u16* __restrict__ qkv,
    const float* __restrict__ pe, const float* __restrict__ qs, const float* __restrict__ ksc,
    u16* __restrict__ Q, u16* __restrict__ Km, u16* __restrict__ Vt) {
  const int h = blockIdx.y;
  const int m = blockIdx.x * 256 + threadIdx.x;
  const float* per = pe + (size_t)m * 256;

  #pragma unroll
  for (int part = 0; part < 2; ++part) {
    const u16* src = qkv + (size_t)m * QKVW + part * DIMC + h * HD;
    const float* sc = part ? ksc : qs;
    const float smul = part ? 1.0f : 0.08838834764831845f;  // 1/sqrt(128) folded into q
    float ssq = 0.f;
    #pragma unroll
    for (int c = 0; c < 16; ++c) {
      uint4 u = *(const uint4*)(src + c * 8);
      float xv[8]; unpack8(u, xv);
      #pragma unroll
      for (int i = 0; i < 8; ++i) ssq += xv[i] * xv[i];
    }
    const float rs = rsqrtf(ssq * (1.0f / 128.0f) + 1e-6f);
    u16* dst = (part ? Km : Q) + ((size_t)h * LQ + m) * HD;
    #pragma unroll
    for (int c = 0; c < 16; ++c) {
      uint4 u = *(const uint4*)(src + c * 8);
      float xv[8]; unpack8(u, xv);
      u32 ow[4];
      #pragma unroll
      for (int pp = 0; pp < 4; ++pp) {
        const int d0 = c * 8 + pp * 2;
        const float t0 = xv[pp * 2]     * rs * sc[d0];
        const float t1 = xv[pp * 2 + 1] * rs * sc[d0 + 1];
        const int p = d0 >> 1;
        const float c0 = per[p * 4 + 0], c1 = per[p * 4 + 1];
        const float c2 = per[p * 4 + 2], c3 = per[p * 4 + 3];
        const u16 e0 = f2bf((c0 * t0 + c1 * t1) * smul);
        const u16 e1 = f2bf((c2 * t0 + c3 * t1) * smul);
        ow[pp] = (u32)e0 | ((u32)e1 << 16);
      }
      uint4 ov; ov.x = ow[0]; ov.y = ow[1]; ov.z = ow[2]; ov.w = ow[3];
      *(uint4*)(dst + c * 8) = ov;
    }
  }
  const u16* vsrc = qkv + (size_t)m * QKVW + 2 * DIMC + h * HD;
  #pragma unroll
  for (int c = 0; c < 16; ++c) {
    uint4 u = *(const uint4*)(vsrc + c * 8);
    u16 e[8];
    e[0] = u.x & 0xFFFF; e[1] = u.x >> 16; e[2] = u.y & 0xFFFF; e[3] = u.y >> 16;
    e[4] = u.z & 0xFFFF; e[5] = u.z >> 16; e[6] = u.w & 0xFFFF; e[7] = u.w >> 16;
    #pragma unroll
    for (int i = 0; i < 8; ++i)
      Vt[((size_t)h * HD + c * 8 + i) * LQ + m] = e[i];
  }
}

// ---------------- flash attention (online softmax, MFMA) ----------------
__global__ __launch_bounds__(256) void attn_kernel(const u16* __restrict__ Q,
    const u16* __restrict__ Km, const u16* __restrict__ Vt, u16* __restrict__ cat) {
  const int h = blockIdx.y;
  const int lane = threadIdx.x & 63, wv = threadIdx.x >> 6;
  const int cidx = lane & 15, rgrp = lane >> 4, kf = rgrp * 8;
  const int m0 = blockIdx.x * 64 + wv * 16;
  const u16* Qh = Q  + (size_t)h * LQ * HD;
  const u16* Kh = Km + (size_t)h * LQ * HD;
  const u16* Vh = Vt + (size_t)h * HD * LQ;

  __shared__ __align__(16) u16 P_all[4][16][72];   // 72 = 64 + 8 pad (bank spread)
  u16 (*P)[72] = P_all[wv];

  bf16x8 qf[4];
  #pragma unroll
  for (int ks = 0; ks < 4; ++ks)
    qf[ks] = *(const bf16x8*)(Qh + (size_t)(m0 + cidx) * HD + ks * 32 + kf);

  f32x4 o[8] = {};
  float mrun[4], lrun[4];
  #pragma unroll
  for (int j = 0; j < 4; ++j) { mrun[j] = -1e30f; lrun[j] = 0.f; }

  for (int nt = 0; nt < LQ; nt += 64) {
    f32x4 s[4] = {};
    #pragma unroll
    for (int ni = 0; ni < 4; ++ni) {
      const u16* kp = Kh + (size_t)(nt + ni * 16 + cidx) * HD + kf;
      #pragma unroll
      for (int ks = 0; ks < 4; ++ks)
        s[ni] = __builtin_amdgcn_mfma_f32_16x16x32_bf16(qf[ks], *(const bf16x8*)(kp + ks * 32), s[ni], 0, 0, 0);
    }
    #pragma unroll
    for (int j = 0; j < 4; ++j) {
      float tm = fmaxf(fmaxf(s[0][j], s[1][j]), fmaxf(s[2][j], s[3][j]));
      #pragma unroll
      for (int off = 1; off < 16; off <<= 1) tm = fmaxf(tm, __shfl_xor(tm, off));
      const float mnew = fmaxf(mrun[j], tm);
      const float corr = __expf(mrun[j] - mnew);
      float rsum = 0.f;
      #pragma unroll
      for (int ni = 0; ni < 4; ++ni) {
        float p = __expf(s[ni][j] - mnew);
        s[ni][j] = p;
        rsum += p;
      }
      #pragma unroll
      for (int off = 1; off < 16; off <<= 1) rsum += __shfl_xor(rsum, off);
      lrun[j] = lrun[j] * corr + rsum;
      mrun[j] = mnew;
      #pragma unroll
      for (int dt = 0; dt < 8; ++dt) o[dt][j] *= corr;
    }
    #pragma unroll
    for (int ni = 0; ni < 4; ++ni)
      #pragma unroll
      for (int j = 0; j < 4; ++j)
        P[rgrp * 4 + j][ni * 16 + cidx] = f2bf(s[ni][j]);
    __syncthreads();
    #pragma unroll
    for (int ks2 = 0; ks2 < 2; ++ks2) {
      bf16x8 pa = *(const bf16x8*)(&P[cidx][ks2 * 32 + kf]);
      #pragma unroll
      for (int dt = 0; dt < 8; ++dt) {
        const u16* vp = Vh + (size_t)(dt * 16 + cidx) * LQ + nt + ks2 * 32 + kf;
        o[dt] = __builtin_amdgcn_mfma_f32_16x16x32_bf16(pa, *(const bf16x8*)vp, o[dt], 0, 0, 0);
      }
    }
    __syncthreads();
  }

  #pragma unroll
  for (int j = 0; j < 4; ++j) {
    const float inv = 1.0f / lrun[j];
    u16* crow = cat + (size_t)(m0 + rgrp * 4 + j) * CATW + h * HD + cidx;
    #pragma unroll
    for (int dt = 0; dt < 8; ++dt)
      crow[dt * 16] = f2bf(o[dt][j] * inv);
  }
}

// ---------------- launch ----------------
extern "C" void kernel_launch(void* const* d_in, const int* in_sizes, int n_in,
                              void* d_out, int out_size, void* d_ws, size_t ws_size,
                              hipStream_t stream) {
  (void)in_sizes; (void)n_in; (void)out_size; (void)ws_size;
  const float* x        = (const float*)d_in[0];
  const float* vec      = (const float*)d_in[1];
  const float* pe       = (const float*)d_in[2];
  const float* mod_w    = (const float*)d_in[3];
  const float* mod_b    = (const float*)d_in[4];
  const float* lin1_w   = (const float*)d_in[5];
  const float* lin1_b   = (const float*)d_in[6];
  const float* lin2_w   = (const float*)d_in[7];
  const float* lin2_b   = (const float*)d_in[8];
  const float* q_scale  = (const float*)d_in[9];
  const float* k_scale  = (const float*)d_in[10];
  const float* qkv_down = (const float*)d_in[11];
  const float* qkv_up   = (const float*)d_in[12];
  const float* proj_down= (const float*)d_in[13];
  const float* proj_up  = (const float*)d_in[14];
  float* outp = (float*)d_out;
  char* ws = (char*)d_ws;

  // workspace layout (~324 MB peak; W2 aliases W1 after GEMM1)
  float* modv  = (float*)(ws + 0);                // 9216 f32
  float* t1    = (float*)(ws + (64ull << 10));    // 2560x16 f32
  float* t2    = (float*)(ws + (320ull << 10));   // 2560x16 f32
  u16* qkvdn_b = (u16*)(ws + (512ull << 10));     // 16x3072 bf16
  u16* qkvup_b = (u16*)(ws + (640ull << 10));     // 9216x16 bf16
  u16* pjdn_b  = (u16*)(ws + (960ull << 10));     // 16x15360 bf16
  u16* pjup_b  = (u16*)(ws + (1472ull << 10));    // 3072x16 bf16
  u16* xmod    = (u16*)(ws + (2ull << 20));       // 2560x3072 bf16
  u16* cat     = (u16*)(ws + (18ull << 20));      // 2560x15360 bf16
  u16* qkvb    = (u16*)(ws + (98ull << 20));      // 2560x9216 bf16
  u16* Qb      = (u16*)(ws + (150ull << 20));     // 24x2560x128 bf16
  u16* Kb      = (u16*)(ws + (166ull << 20));
  u16* Vb      = (u16*)(ws + (182ull << 20));     // transposed [24][128][2560]
  u16* w1b     = (u16*)(ws + (198ull << 20));     // 21504x3072 bf16
  u16* w2b     = w1b;                             // 3072x15360 bf16 (alias, post-GEMM1)

  cvt_bf16<<<64, 256, 0, stream>>>(qkv_down,  qkvdn_b, (long)RK * DIMC);
  cvt_bf16<<<64, 256, 0, stream>>>(qkv_up,    qkvup_b, (long)QKVW * RK);
  cvt_bf16<<<64, 256, 0, stream>>>(proj_down, pjdn_b,  (long)RK * CATW);
  cvt_bf16<<<64, 256, 0, stream>>>(proj_up,   pjup_b,  (long)DIMC * RK);
  cvt_bf16<<<4096, 256, 0, stream>>>(lin1_w, w1b, (long)NTOT * DIMC);

  mod_kernel<<<QKVW / 4, 256, 0, stream>>>(vec, mod_w, mod_b, modv);
  ln_mod<<<LQ, 256, 0, stream>>>(x, modv, xmod);
  lora_down<<<LQ, 256, 0, stream>>>(xmod, qkvdn_b, t1, DIMC);

  gemm128<0><<<dim3(NTOT / 128, LQ / 128), 256, 0, stream>>>(
      xmod, w1b, DIMC, lin1_b, qkvup_b, t1, qkvb, cat, nullptr, nullptr, nullptr);

  cvt_bf16<<<4096, 256, 0, stream>>>(lin2_w, w2b, (long)DIMC * CATW);

  qkv_prep<<<dim3(LQ / 256, NH), 256, 0, stream>>>(qkvb, pe, q_scale, k_scale, Qb, Kb, Vb);
  attn_kernel<<<dim3(LQ / 64, NH), 256, 0, stream>>>(Qb, Kb, Vb, cat);

  lora_down<<<LQ, 256, 0, stream>>>(cat, pjdn_b, t2, CATW);

  gemm128<1><<<dim3(DIMC / 128, LQ / 128), 256, 0, stream>>>(
      cat, w2b, CATW, lin2_b, pjup_b, t2, nullptr, nullptr, x, modv + 2 * DIMC, outp);
}

// Round 5
// 2089.099 us; speedup vs baseline: 1.6116x; 1.6116x over previous
//
#include <hip/hip_runtime.h>

// SingleStreamBlockLoraProcessor — MI355X bf16 MFMA implementation.
// Round 4 (resubmit; rounds 2-4 hit GPU-acquisition timeouts): deep-pipelined
// GEMMs (BK=32, 4 LDS buffers, counted vmcnt, T2 swizzle, T5 setprio, T1 XCD
// block swizzle). Attention/prep unchanged from round 1.

using u16 = unsigned short;
using u32 = unsigned int;

typedef __attribute__((ext_vector_type(8))) __bf16 bf16x8;
typedef __attribute__((ext_vector_type(4))) float f32x4;

#define DEV static __device__ __forceinline__

constexpr int LQ   = 2560;
constexpr int DIMC = 3072;
constexpr int NH   = 24;
constexpr int HD   = 128;
constexpr int NTOT = 21504;   // 3*DIM + MLP
constexpr int QKVW = 9216;    // 3*DIM
constexpr int CATW = 15360;   // DIM + MLP
constexpr int RK   = 16;

DEV u16 f2bf(float f) {
  union { float f; u32 u; } v; v.f = f;
  u32 r = v.u + 0x7FFFu + ((v.u >> 16) & 1u);
  return (u16)(r >> 16);
}
DEV float bflo(u32 u) { union { u32 u; float f; } v; v.u = u << 16; return v.f; }
DEV float bfhi(u32 u) { union { u32 u; float f; } v; v.u = u & 0xFFFF0000u; return v.f; }
DEV void unpack8(uint4 u, float* f) {
  f[0]=bflo(u.x); f[1]=bfhi(u.x); f[2]=bflo(u.y); f[3]=bfhi(u.y);
  f[4]=bflo(u.z); f[5]=bfhi(u.z); f[6]=bflo(u.w); f[7]=bfhi(u.w);
}
DEV void gload_lds16(const void* g, void* l) {
  __builtin_amdgcn_global_load_lds((const __attribute__((address_space(1))) void*)g,
                                   (__attribute__((address_space(3))) void*)l, 16, 0, 0);
}
DEV float gelu_tanh(float v) {
  float u = 0.7978845608028654f * (v + 0.044715f * v * v * v);
  float e = __expf(2.0f * u);
  float t = 1.0f - 2.0f / (e + 1.0f);
  return 0.5f * v * (1.0f + t);
}

#define VMW(n) asm volatile("s_waitcnt vmcnt(" #n ")" ::: "memory")

// ---------------- fp32 -> bf16 conversion ----------------
__global__ __launch_bounds__(256) void cvt_bf16(const float* __restrict__ in,
                                                u16* __restrict__ out, long n) {
  long i = ((long)blockIdx.x * 256 + threadIdx.x) * 8;
  const long stride = (long)gridDim.x * 256 * 8;
  for (; i < n; i += stride) {
    float4 a = *(const float4*)(in + i);
    float4 b = *(const float4*)(in + i + 4);
    uint4 o;
    o.x = (u32)f2bf(a.x) | ((u32)f2bf(a.y) << 16);
    o.y = (u32)f2bf(a.z) | ((u32)f2bf(a.w) << 16);
    o.z = (u32)f2bf(b.x) | ((u32)f2bf(b.y) << 16);
    o.w = (u32)f2bf(b.z) | ((u32)f2bf(b.w) << 16);
    *(uint4*)(out + i) = o;
  }
}

// ---------------- mod = silu(vec) @ mod_w.T + mod_b ----------------
__global__ __launch_bounds__(256) void mod_kernel(const float* __restrict__ vec,
    const float* __restrict__ mw, const float* __restrict__ mb, float* __restrict__ mo) {
  const int j = blockIdx.x * 4 + (threadIdx.x >> 6);
  const int lane = threadIdx.x & 63;
  const float* wr_ = mw + (size_t)j * DIMC;
  float s = 0.f;
  for (int i = lane * 4; i < DIMC; i += 256) {
    float4 w4 = *(const float4*)(wr_ + i);
    float4 v4 = *(const float4*)(vec + i);
    float s0 = v4.x / (1.f + __expf(-v4.x));
    float s1 = v4.y / (1.f + __expf(-v4.y));
    float s2 = v4.z / (1.f + __expf(-v4.z));
    float s3 = v4.w / (1.f + __expf(-v4.w));
    s += s0 * w4.x + s1 * w4.y + s2 * w4.z + s3 * w4.w;
  }
  #pragma unroll
  for (int o = 32; o; o >>= 1) s += __shfl_down(s, o);
  if (lane == 0) mo[j] = s + mb[j];
}

// ---------------- LayerNorm + modulate -> x_mod (bf16) ----------------
__global__ __launch_bounds__(256) void ln_mod(const float* __restrict__ x,
    const float* __restrict__ modv, u16* __restrict__ xmod) {
  const int row = blockIdx.x, tid = threadIdx.x;
  const float* xr = x + (size_t)row * DIMC;
  float4 v0 = *(const float4*)(xr + tid * 4);
  float4 v1 = *(const float4*)(xr + tid * 4 + 1024);
  float4 v2 = *(const float4*)(xr + tid * 4 + 2048);
  float s  = v0.x + v0.y + v0.z + v0.w + v1.x + v1.y + v1.z + v1.w + v2.x + v2.y + v2.z + v2.w;
  float ss = v0.x*v0.x + v0.y*v0.y + v0.z*v0.z + v0.w*v0.w
           + v1.x*v1.x + v1.y*v1.y + v1.z*v1.z + v1.w*v1.w
           + v2.x*v2.x + v2.y*v2.y + v2.z*v2.z + v2.w*v2.w;
  #pragma unroll
  for (int o = 32; o; o >>= 1) { s += __shfl_down(s, o); ss += __shfl_down(ss, o); }
  __shared__ float rs[4], rss[4];
  const int lane = tid & 63, wv = tid >> 6;
  if (lane == 0) { rs[wv] = s; rss[wv] = ss; }
  __syncthreads();
  s = rs[0] + rs[1] + rs[2] + rs[3]; ss = rss[0] + rss[1] + rss[2] + rss[3];
  const float mu = s * (1.0f / 3072.0f);
  const float rstd = rsqrtf(ss * (1.0f / 3072.0f) - mu * mu + 1e-6f);
  u16* orow = xmod + (size_t)row * DIMC;
  #pragma unroll
  for (int p = 0; p < 3; ++p) {
    const int c = tid * 4 + p * 1024;
    const float4 v = (p == 0) ? v0 : ((p == 1) ? v1 : v2);
    const float4 scv = *(const float4*)(modv + DIMC + c);
    const float4 shv = *(const float4*)(modv + c);
    u32 w0 = (u32)f2bf((1.f + scv.x) * ((v.x - mu) * rstd) + shv.x)
           | ((u32)f2bf((1.f + scv.y) * ((v.y - mu) * rstd) + shv.y) << 16);
    u32 w1 = (u32)f2bf((1.f + scv.z) * ((v.z - mu) * rstd) + shv.z)
           | ((u32)f2bf((1.f + scv.w) * ((v.w - mu) * rstd) + shv.w) << 16);
    uint2 o; o.x = w0; o.y = w1;
    *(uint2*)(orow + c) = o;
  }
}

// ---------------- LoRA down: T[m][16] = X[m][:] @ Wd[16][:]^T ----------------
__global__ __launch_bounds__(256) void lora_down(const u16* __restrict__ X,
    const u16* __restrict__ Wd, float* __restrict__ T, int K) {
  const int m = blockIdx.x;
  const int lane = threadIdx.x & 63, wv = threadIdx.x >> 6;
  const u16* xr = X + (size_t)m * K;
  float a0 = 0, a1 = 0, a2 = 0, a3 = 0;
  for (int c = lane * 8; c < K; c += 512) {
    uint4 xu = *(const uint4*)(xr + c);
    float xv[8]; unpack8(xu, xv);
    float w0[8], w1[8], w2[8], w3[8];
    unpack8(*(const uint4*)(Wd + (size_t)(wv * 4 + 0) * K + c), w0);
    unpack8(*(const uint4*)(Wd + (size_t)(wv * 4 + 1) * K + c), w1);
    unpack8(*(const uint4*)(Wd + (size_t)(wv * 4 + 2) * K + c), w2);
    unpack8(*(const uint4*)(Wd + (size_t)(wv * 4 + 3) * K + c), w3);
    #pragma unroll
    for (int i = 0; i < 8; ++i) {
      a0 += xv[i] * w0[i]; a1 += xv[i] * w1[i];
      a2 += xv[i] * w2[i]; a3 += xv[i] * w3[i];
    }
  }
  #pragma unroll
  for (int o = 32; o; o >>= 1) {
    a0 += __shfl_down(a0, o); a1 += __shfl_down(a1, o);
    a2 += __shfl_down(a2, o); a3 += __shfl_down(a3, o);
  }
  if (lane == 0) {
    float* tp = T + (size_t)m * RK + wv * 4;
    tp[0] = a0; tp[1] = a1; tp[2] = a2; tp[3] = a3;
  }
}

// ---------------- deep-pipelined MFMA GEMM, C = A @ W^T (+ fused epilogues) ----
// MODE 0: BM=256,BN=256  GEMM1 -> qkv (bias+LoRA-up) bf16 + gelu(mlp) into cat
// MODE 1: BM=256,BN=128  GEMM2 -> out = x + gate*(acc+bias+LoRA-up), fp32
// Structure: BK=32, 4 LDS buffers (lookahead-3), counted vmcnt (8/4/0 tail),
// ONE s_barrier per K-step, setprio around MFMA cluster, T2 chunk-XOR swizzle
// applied to the per-lane GLOBAL source (LDS dest stays lane-linear) and to the
// ds_read address.
template<int MODE>
__global__ __launch_bounds__(512, 2)
void gemm256(const u16* __restrict__ A, const u16* __restrict__ W, int K,
             const float* __restrict__ bias, const u16* __restrict__ up,
             const float* __restrict__ tlow,
             u16* __restrict__ out_qkv, u16* __restrict__ out_cat,
             const float* __restrict__ xres, const float* __restrict__ gate,
             float* __restrict__ outf) {
  constexpr int BN    = MODE ? 128 : 256;
  constexpr int MREP  = MODE ? 4 : 8;      // A fragments per wave
  constexpr int AELEM = 256 * 32;          // u16 elems per A tile
  constexpr int BELEM = BN * 32;
  constexpr int BUFE  = AELEM + BELEM;
  constexpr int BPASS = (BN * 4) / 512;    // B stage passes per thread (2 or 1)
  __shared__ u16 lds[4 * BUFE];

  const int tid  = threadIdx.x;
  const int lane = tid & 63, wv = tid >> 6;
  const int cidx = lane & 15, rgrp = lane >> 4;
  const int wm = MODE ? (wv >> 1) : (wv >> 2);
  const int wn = MODE ? (wv & 1) : (wv & 3);

  // T1: bijective XCD chunking (gridDim.x divisible by 8; M-blocks = 10)
  const int chunk = gridDim.x >> 3;
  const int flat  = ((int)blockIdx.x & 7) * chunk + ((int)blockIdx.x >> 3);
  const int bx = flat / 10, by = flat % 10;
  const int bm = by * 256, bn = bx * BN;

  // staging source addresses (per-lane, chunk pre-swizzled: rule #21)
  const u16* srcA[2]; const u16* srcB[BPASS ? BPASS : 1];
  #pragma unroll
  for (int j = 0; j < 2; ++j) {
    const int seg = (j * 8 + wv) * 64 + lane;
    const int row = seg >> 2, cd = (seg & 3) ^ (row & 3);
    srcA[j] = A + (size_t)(bm + row) * K + cd * 8;
  }
  #pragma unroll
  for (int j = 0; j < BPASS; ++j) {
    const int seg = (j * 8 + wv) * 64 + lane;
    const int row = seg >> 2, cd = (seg & 3) ^ (row & 3);
    srcB[j] = W + (size_t)(bn + row) * K + cd * 8;
  }

  const int NT = K / 32;
  auto stage = [&](int t) {
    u16* base = lds + (t & 3) * BUFE;
    const int koff = t * 32;
    #pragma unroll
    for (int j = 0; j < 2; ++j)
      gload_lds16(srcA[j] + koff, base + (j * 8 + wv) * 512);
    #pragma unroll
    for (int j = 0; j < BPASS; ++j)
      gload_lds16(srcB[j] + koff, base + AELEM + (j * 8 + wv) * 512);
  };

  // ds_read base offsets (swizzled chunk slot: rgrp ^ (row&3), row&3 == cidx&3)
  const int csl  = rgrp ^ (cidx & 3);
  const int arof = (wm * (MREP * 16) + cidx) * 32 + csl * 8;
  const int brof = AELEM + (wn * 64 + cidx) * 32 + csl * 8;

  f32x4 acc[MREP][4] = {};

  stage(0); stage(1); stage(2);

  for (int t = 0; t < NT; ++t) {
    if (t + 2 < NT)      { if constexpr (MODE == 0) VMW(8); else VMW(6); }
    else if (t + 1 < NT) { if constexpr (MODE == 0) VMW(4); else VMW(3); }
    else                 VMW(0);
    __builtin_amdgcn_s_barrier();
    asm volatile("" ::: "memory");
    if (t + 3 < NT) stage(t + 3);
    const u16* bufp = lds + (t & 3) * BUFE;
    bf16x8 af[MREP], bfr[4];
    #pragma unroll
    for (int mi = 0; mi < MREP; ++mi)
      af[mi] = *(const bf16x8*)(bufp + arof + mi * 512);
    #pragma unroll
    for (int ni = 0; ni < 4; ++ni)
      bfr[ni] = *(const bf16x8*)(bufp + brof + ni * 512);
    __builtin_amdgcn_s_setprio(1);
    #pragma unroll
    for (int mi = 0; mi < MREP; ++mi)
      #pragma unroll
      for (int ni = 0; ni < 4; ++ni)
        acc[mi][ni] = __builtin_amdgcn_mfma_f32_16x16x32_bf16(af[mi], bfr[ni], acc[mi][ni], 0, 0, 0);
    __builtin_amdgcn_s_setprio(0);
  }

  // ------------- epilogues -------------
  if constexpr (MODE == 0) {
    const int rowb = bm + wm * 128;
    if (bn < QKVW) {
      float upv[4][16]; float bia[4]; int nn[4];
      #pragma unroll
      for (int ni = 0; ni < 4; ++ni) {
        const int n = bn + wn * 64 + ni * 16 + cidx;
        nn[ni] = n; bia[ni] = bias[n];
        unpack8(*(const uint4*)(up + (size_t)n * RK), upv[ni]);
        unpack8(*(const uint4*)(up + (size_t)n * RK + 8), upv[ni] + 8);
      }
      #pragma unroll
      for (int mi = 0; mi < 8; ++mi) {
        #pragma unroll
        for (int j = 0; j < 4; ++j) {
          const int m = rowb + mi * 16 + rgrp * 4 + j;
          const float* tp = tlow + (size_t)m * RK;
          float tr[16];
          *(float4*)(tr)      = *(const float4*)(tp);
          *(float4*)(tr + 4)  = *(const float4*)(tp + 4);
          *(float4*)(tr + 8)  = *(const float4*)(tp + 8);
          *(float4*)(tr + 12) = *(const float4*)(tp + 12);
          #pragma unroll
          for (int ni = 0; ni < 4; ++ni) {
            float v = acc[mi][ni][j] + bia[ni];
            #pragma unroll
            for (int i = 0; i < 16; ++i) v += tr[i] * upv[ni][i];
            out_qkv[(size_t)m * QKVW + nn[ni]] = f2bf(v);
          }
        }
      }
    } else {
      float bia[4]; int nn[4];
      #pragma unroll
      for (int ni = 0; ni < 4; ++ni) {
        const int n = bn + wn * 64 + ni * 16 + cidx;
        nn[ni] = n - 2 * DIMC; bia[ni] = bias[n];
      }
      #pragma unroll
      for (int mi = 0; mi < 8; ++mi) {
        #pragma unroll
        for (int j = 0; j < 4; ++j) {
          const int m = rowb + mi * 16 + rgrp * 4 + j;
          #pragma unroll
          for (int ni = 0; ni < 4; ++ni)
            out_cat[(size_t)m * CATW + nn[ni]] = f2bf(gelu_tanh(acc[mi][ni][j] + bia[ni]));
        }
      }
    }
  } else {
    const int rowb = bm + wm * 64;
    float upv[4][16]; float bia[4], gg[4]; int nn[4];
    #pragma unroll
    for (int ni = 0; ni < 4; ++ni) {
      const int n = bn + wn * 64 + ni * 16 + cidx;
      nn[ni] = n; bia[ni] = bias[n]; gg[ni] = gate[n];
      unpack8(*(const uint4*)(up + (size_t)n * RK), upv[ni]);
      unpack8(*(const uint4*)(up + (size_t)n * RK + 8), upv[ni] + 8);
    }
    #pragma unroll
    for (int mi = 0; mi < 4; ++mi) {
      #pragma unroll
      for (int j = 0; j < 4; ++j) {
        const int m = rowb + mi * 16 + rgrp * 4 + j;
        const float* tp = tlow + (size_t)m * RK;
        float tr[16];
        *(float4*)(tr)      = *(const float4*)(tp);
        *(float4*)(tr + 4)  = *(const float4*)(tp + 4);
        *(float4*)(tr + 8)  = *(const float4*)(tp + 8);
        *(float4*)(tr + 12) = *(const float4*)(tp + 12);
        #pragma unroll
        for (int ni = 0; ni < 4; ++ni) {
          float v = acc[mi][ni][j] + bia[ni];
          #pragma unroll
          for (int i = 0; i < 16; ++i) v += tr[i] * upv[ni][i];
          outf[(size_t)m * DIMC + nn[ni]] = xres[(size_t)m * DIMC + nn[ni]] + gg[ni] * v;
        }
      }
    }
  }
}

// ---------------- qkv prep: RMS-norm + RoPE, V transpose ----------------
__global__ __launch_bounds__(256) void qkv_prep(const u16* __restrict__ qkv,
    const float* __restrict__ pe, const float* __restrict__ qs, const float* __restrict__ ksc,
    u16* __restrict__ Q, u16* __restrict__ Km, u16* __restrict__ Vt) {
  const int h = blockIdx.y;
  const int m = blockIdx.x * 256 + threadIdx.x;
  const float* per = pe + (size_t)m * 256;

  #pragma unroll
  for (int part = 0; part < 2; ++part) {
    const u16* src = qkv + (size_t)m * QKVW + part * DIMC + h * HD;
    const float* sc = part ? ksc : qs;
    const float smul = part ? 1.0f : 0.08838834764831845f;  // 1/sqrt(128) folded into q
    float ssq = 0.f;
    #pragma unroll
    for (int c = 0; c < 16; ++c) {
      uint4 u = *(const uint4*)(src + c * 8);
      float xv[8]; unpack8(u, xv);
      #pragma unroll
      for (int i = 0; i < 8; ++i) ssq += xv[i] * xv[i];
    }
    const float rs = rsqrtf(ssq * (1.0f / 128.0f) + 1e-6f);
    u16* dst = (part ? Km : Q) + ((size_t)h * LQ + m) * HD;
    #pragma unroll
    for (int c = 0; c < 16; ++c) {
      uint4 u = *(const uint4*)(src + c * 8);
      float xv[8]; unpack8(u, xv);
      u32 ow[4];
      #pragma unroll
      for (int pp = 0; pp < 4; ++pp) {
        const int d0 = c * 8 + pp * 2;
        const float t0 = xv[pp * 2]     * rs * sc[d0];
        const float t1 = xv[pp * 2 + 1] * rs * sc[d0 + 1];
        const int p = d0 >> 1;
        const float c0 = per[p * 4 + 0], c1 = per[p * 4 + 1];
        const float c2 = per[p * 4 + 2], c3 = per[p * 4 + 3];
        const u16 e0 = f2bf((c0 * t0 + c1 * t1) * smul);
        const u16 e1 = f2bf((c2 * t0 + c3 * t1) * smul);
        ow[pp] = (u32)e0 | ((u32)e1 << 16);
      }
      uint4 ov; ov.x = ow[0]; ov.y = ow[1]; ov.z = ow[2]; ov.w = ow[3];
      *(uint4*)(dst + c * 8) = ov;
    }
  }
  const u16* vsrc = qkv + (size_t)m * QKVW + 2 * DIMC + h * HD;
  #pragma unroll
  for (int c = 0; c < 16; ++c) {
    uint4 u = *(const uint4*)(vsrc + c * 8);
    u16 e[8];
    e[0] = u.x & 0xFFFF; e[1] = u.x >> 16; e[2] = u.y & 0xFFFF; e[3] = u.y >> 16;
    e[4] = u.z & 0xFFFF; e[5] = u.z >> 16; e[6] = u.w & 0xFFFF; e[7] = u.w >> 16;
    #pragma unroll
    for (int i = 0; i < 8; ++i)
      Vt[((size_t)h * HD + c * 8 + i) * LQ + m] = e[i];
  }
}

// ---------------- flash attention (online softmax, MFMA) ----------------
__global__ __launch_bounds__(256) void attn_kernel(const u16* __restrict__ Q,
    const u16* __restrict__ Km, const u16* __restrict__ Vt, u16* __restrict__ cat) {
  const int h = blockIdx.y;
  const int lane = threadIdx.x & 63, wv = threadIdx.x >> 6;
  const int cidx = lane & 15, rgrp = lane >> 4, kf = rgrp * 8;
  const int m0 = blockIdx.x * 64 + wv * 16;
  const u16* Qh = Q  + (size_t)h * LQ * HD;
  const u16* Kh = Km + (size_t)h * LQ * HD;
  const u16* Vh = Vt + (size_t)h * HD * LQ;

  __shared__ __align__(16) u16 P_all[4][16][72];   // 72 = 64 + 8 pad (bank spread)
  u16 (*P)[72] = P_all[wv];

  bf16x8 qf[4];
  #pragma unroll
  for (int ks = 0; ks < 4; ++ks)
    qf[ks] = *(const bf16x8*)(Qh + (size_t)(m0 + cidx) * HD + ks * 32 + kf);

  f32x4 o[8] = {};
  float mrun[4], lrun[4];
  #pragma unroll
  for (int j = 0; j < 4; ++j) { mrun[j] = -1e30f; lrun[j] = 0.f; }

  for (int nt = 0; nt < LQ; nt += 64) {
    f32x4 s[4] = {};
    #pragma unroll
    for (int ni = 0; ni < 4; ++ni) {
      const u16* kp = Kh + (size_t)(nt + ni * 16 + cidx) * HD + kf;
      #pragma unroll
      for (int ks = 0; ks < 4; ++ks)
        s[ni] = __builtin_amdgcn_mfma_f32_16x16x32_bf16(qf[ks], *(const bf16x8*)(kp + ks * 32), s[ni], 0, 0, 0);
    }
    #pragma unroll
    for (int j = 0; j < 4; ++j) {
      float tm = fmaxf(fmaxf(s[0][j], s[1][j]), fmaxf(s[2][j], s[3][j]));
      #pragma unroll
      for (int off = 1; off < 16; off <<= 1) tm = fmaxf(tm, __shfl_xor(tm, off));
      const float mnew = fmaxf(mrun[j], tm);
      const float corr = __expf(mrun[j] - mnew);
      float rsum = 0.f;
      #pragma unroll
      for (int ni = 0; ni < 4; ++ni) {
        float p = __expf(s[ni][j] - mnew);
        s[ni][j] = p;
        rsum += p;
      }
      #pragma unroll
      for (int off = 1; off < 16; off <<= 1) rsum += __shfl_xor(rsum, off);
      lrun[j] = lrun[j] * corr + rsum;
      mrun[j] = mnew;
      #pragma unroll
      for (int dt = 0; dt < 8; ++dt) o[dt][j] *= corr;
    }
    #pragma unroll
    for (int ni = 0; ni < 4; ++ni)
      #pragma unroll
      for (int j = 0; j < 4; ++j)
        P[rgrp * 4 + j][ni * 16 + cidx] = f2bf(s[ni][j]);
    __syncthreads();
    #pragma unroll
    for (int ks2 = 0; ks2 < 2; ++ks2) {
      bf16x8 pa = *(const bf16x8*)(&P[cidx][ks2 * 32 + kf]);
      #pragma unroll
      for (int dt = 0; dt < 8; ++dt) {
        const u16* vp = Vh + (size_t)(dt * 16 + cidx) * LQ + nt + ks2 * 32 + kf;
        o[dt] = __builtin_amdgcn_mfma_f32_16x16x32_bf16(pa, *(const bf16x8*)vp, o[dt], 0, 0, 0);
      }
    }
    __syncthreads();
  }

  #pragma unroll
  for (int j = 0; j < 4; ++j) {
    const float inv = 1.0f / lrun[j];
    u16* crow = cat + (size_t)(m0 + rgrp * 4 + j) * CATW + h * HD + cidx;
    #pragma unroll
    for (int dt = 0; dt < 8; ++dt)
      crow[dt * 16] = f2bf(o[dt][j] * inv);
  }
}

// ---------------- launch ----------------
extern "C" void kernel_launch(void* const* d_in, const int* in_sizes, int n_in,
                              void* d_out, int out_size, void* d_ws, size_t ws_size,
                              hipStream_t stream) {
  (void)in_sizes; (void)n_in; (void)out_size; (void)ws_size;
  const float* x        = (const float*)d_in[0];
  const float* vec      = (const float*)d_in[1];
  const float* pe       = (const float*)d_in[2];
  const float* mod_w    = (const float*)d_in[3];
  const float* mod_b    = (const float*)d_in[4];
  const float* lin1_w   = (const float*)d_in[5];
  const float* lin1_b   = (const float*)d_in[6];
  const float* lin2_w   = (const float*)d_in[7];
  const float* lin2_b   = (const float*)d_in[8];
  const float* q_scale  = (const float*)d_in[9];
  const float* k_scale  = (const float*)d_in[10];
  const float* qkv_down = (const float*)d_in[11];
  const float* qkv_up   = (const float*)d_in[12];
  const float* proj_down= (const float*)d_in[13];
  const float* proj_up  = (const float*)d_in[14];
  float* outp = (float*)d_out;
  char* ws = (char*)d_ws;

  // workspace layout (~330 MB peak; W2 aliases W1 after GEMM1)
  float* modv  = (float*)(ws + 0);                // 9216 f32
  float* t1    = (float*)(ws + (64ull << 10));    // 2560x16 f32
  float* t2    = (float*)(ws + (320ull << 10));   // 2560x16 f32
  u16* qkvdn_b = (u16*)(ws + (512ull << 10));     // 16x3072 bf16
  u16* qkvup_b = (u16*)(ws + (640ull << 10));     // 9216x16 bf16
  u16* pjdn_b  = (u16*)(ws + (960ull << 10));     // 16x15360 bf16
  u16* pjup_b  = (u16*)(ws + (1472ull << 10));    // 3072x16 bf16
  u16* xmod    = (u16*)(ws + (2ull << 20));       // 2560x3072 bf16
  u16* cat     = (u16*)(ws + (18ull << 20));      // 2560x15360 bf16
  u16* qkvb    = (u16*)(ws + (98ull << 20));      // 2560x9216 bf16
  u16* Qb      = (u16*)(ws + (150ull << 20));     // 24x2560x128 bf16
  u16* Kb      = (u16*)(ws + (166ull << 20));
  u16* Vb      = (u16*)(ws + (182ull << 20));     // transposed [24][128][2560]
  u16* w1b     = (u16*)(ws + (198ull << 20));     // 21504x3072 bf16
  u16* w2b     = w1b;                             // 3072x15360 bf16 (alias, post-GEMM1)

  cvt_bf16<<<64, 256, 0, stream>>>(qkv_down,  qkvdn_b, (long)RK * DIMC);
  cvt_bf16<<<64, 256, 0, stream>>>(qkv_up,    qkvup_b, (long)QKVW * RK);
  cvt_bf16<<<64, 256, 0, stream>>>(proj_down, pjdn_b,  (long)RK * CATW);
  cvt_bf16<<<64, 256, 0, stream>>>(proj_up,   pjup_b,  (long)DIMC * RK);
  cvt_bf16<<<4096, 256, 0, stream>>>(lin1_w, w1b, (long)NTOT * DIMC);

  mod_kernel<<<QKVW / 4, 256, 0, stream>>>(vec, mod_w, mod_b, modv);
  ln_mod<<<LQ, 256, 0, stream>>>(x, modv, xmod);
  lora_down<<<LQ, 256, 0, stream>>>(xmod, qkvdn_b, t1, DIMC);

  // GEMM1: 84 x 10 = 840 blocks (8 x 105, XCD-chunked in-kernel)
  gemm256<0><<<840, 512, 0, stream>>>(
      xmod, w1b, DIMC, lin1_b, qkvup_b, t1, qkvb, cat, nullptr, nullptr, nullptr);

  cvt_bf16<<<4096, 256, 0, stream>>>(lin2_w, w2b, (long)DIMC * CATW);

  qkv_prep<<<dim3(LQ / 256, NH), 256, 0, stream>>>(qkvb, pe, q_scale, k_scale, Qb, Kb, Vb);
  attn_kernel<<<dim3(LQ / 64, NH), 256, 0, stream>>>(Qb, Kb, Vb, cat);

  lora_down<<<LQ, 256, 0, stream>>>(cat, pjdn_b, t2, CATW);

  // GEMM2: 24 x 10 = 240 blocks (8 x 30)
  gemm256<1><<<240, 512, 0, stream>>>(
      cat, w2b, CATW, lin2_b, pjup_b, t2, nullptr, nullptr, x, modv + 2 * DIMC, outp);
}